// Round 2
// baseline (1422.510 us; speedup 1.0000x reference)
//
#include <hip/hip_runtime.h>
#include <stdint.h>

#define BATCH 8
#define C 128
#define TPB 512
#define GEMM_BLOCKS 512   // 2 blocks/CU (64KB LDS each)

// order-preserving float -> uint key (monotone: a<b  <=>  key(a)<key(b))
__device__ __forceinline__ unsigned f2key(float f){
  unsigned b = __float_as_uint(f);
  return (b & 0x80000000u) ? ~b : (b | 0x80000000u);
}

// ---------------------------------------------------------------------------
// GEMM: h = relu(fea@W1+b1) -> out ; p = h@W2+b2 (f64 accum) -> pred ;
// segment max of key(p) via atomicMax.
// fea: direct wave-uniform global loads (VMEM pipe, L1-line reuse across
// k-groups).  W1: LDS, transposed, XOR-swizzled 16B chunks so the per-lane
// ds_read_b128 spreads across all 32 banks.  No barriers in the main loop.
// Each wave owns 8 consecutive rows ("octet"); lane owns cols (2L, 2L+1).
// FMA order per accumulator is bit-identical to the previous passing kernel.
// ---------------------------------------------------------------------------
__global__ __launch_bounds__(TPB, 4) void k_gemm(
    const float* __restrict__ fea, const float* __restrict__ W1,
    const float* __restrict__ b1, const float* __restrict__ W2,
    const float* __restrict__ b2, const int* __restrict__ vox,
    float* __restrict__ out, float* __restrict__ pred,
    unsigned* __restrict__ segkey, int N)
{
  // sW1t[c][k'] = W1[k][c], with 16B-chunk swizzle: chunk' = (k>>2) ^ ((c>>1)&7)
  __shared__ float sW1t[C * C];   // 64KB

  const int tid  = threadIdx.x;
  const int lane = tid & 63;
  const int wid  = tid >> 6;
  const int c0   = lane * 2;
  const int swz  = lane & 7;

  for (int idx = tid; idx < C * C; idx += TPB) {
    int k = idx >> 7, c = idx & 127;
    int chunk = (k >> 2) ^ ((c >> 1) & 7);
    sW1t[c * C + (chunk << 2) + (k & 3)] = W1[idx];
  }
  __syncthreads();

  const float bb0 = b1[c0], bb1 = b1[c0 + 1];
  const float w20 = W2[c0], w21 = W2[c0 + 1];
  const double b2d = (double)b2[0];

  const float* wb0 = &sW1t[c0 * C];
  const float* wb1 = &sW1t[(c0 + 1) * C];

  const int nOct = N >> 3;                    // 100000
  const int gw = blockIdx.x * 8 + wid;        // global wave id
  const int nw = GEMM_BLOCKS * 8;

  for (int oct = gw; oct < nOct; oct += nw) {
    const float* frow = fea + (size_t)oct * (8 * C);
    float4 fA[8], fB[8];
    float a0[8], a1[8];
    #pragma unroll
    for (int j = 0; j < 8; ++j) { a0[j] = bb0; a1[j] = bb1; }
    #pragma unroll
    for (int j = 0; j < 8; ++j) fA[j] = *(const float4*)(frow + j * C);

    #pragma unroll 1
    for (int kg = 0; kg < 32; kg += 2) {
      // prefetch kg+1 (always in range: kg <= 30)
      #pragma unroll
      for (int j = 0; j < 8; ++j)
        fB[j] = *(const float4*)(frow + j * C + (kg + 1) * 4);
      {
        const int ch = ((kg ^ swz) << 2);
        float4 wa = *(const float4*)(wb0 + ch);
        float4 wb = *(const float4*)(wb1 + ch);
        #pragma unroll
        for (int j = 0; j < 8; ++j) {
          float4 f = fA[j];
          a0[j] = fmaf(f.x, wa.x, a0[j]); a1[j] = fmaf(f.x, wb.x, a1[j]);
          a0[j] = fmaf(f.y, wa.y, a0[j]); a1[j] = fmaf(f.y, wb.y, a1[j]);
          a0[j] = fmaf(f.z, wa.z, a0[j]); a1[j] = fmaf(f.z, wb.z, a1[j]);
          a0[j] = fmaf(f.w, wa.w, a0[j]); a1[j] = fmaf(f.w, wb.w, a1[j]);
        }
      }
      if (kg + 2 < 32) {
        #pragma unroll
        for (int j = 0; j < 8; ++j)
          fA[j] = *(const float4*)(frow + j * C + (kg + 2) * 4);
      }
      {
        const int ch = (((kg + 1) ^ swz) << 2);
        float4 wa = *(const float4*)(wb0 + ch);
        float4 wb = *(const float4*)(wb1 + ch);
        #pragma unroll
        for (int j = 0; j < 8; ++j) {
          float4 f = fB[j];
          a0[j] = fmaf(f.x, wa.x, a0[j]); a1[j] = fmaf(f.x, wb.x, a1[j]);
          a0[j] = fmaf(f.y, wa.y, a0[j]); a1[j] = fmaf(f.y, wb.y, a1[j]);
          a0[j] = fmaf(f.z, wa.z, a0[j]); a1[j] = fmaf(f.z, wb.z, a1[j]);
          a0[j] = fmaf(f.w, wa.w, a0[j]); a1[j] = fmaf(f.w, wb.w, a1[j]);
        }
      }
    }

    #pragma unroll
    for (int j = 0; j < 8; ++j) {
      const int row = oct * 8 + j;
      const float h0 = fmaxf(a0[j], 0.f), h1 = fmaxf(a1[j], 0.f);
      *(float2*)&out[(size_t)row * C + c0] = make_float2(h0, h1);
      double pd = (double)h0 * (double)w20 + (double)h1 * (double)w21;
      #pragma unroll
      for (int off = 32; off >= 1; off >>= 1) pd += __shfl_xor(pd, off, 64);
      if (lane == 0) {
        const float pv = (float)(pd + b2d);
        pred[row] = pv;
        atomicMax(&segkey[vox[row]], f2key(pv));
      }
    }
  }
}

// ---------------------------------------------------------------------------
// valkey[i] = (p_i is its voxel's max) ? 0xFFFFFFFF (= +inf) : key(p_i)
// + per-row histogram of high 16 key bits.
// ---------------------------------------------------------------------------
__global__ void k_mask_hist1(const float* __restrict__ pred,
                             const int* __restrict__ vox,
                             const unsigned* __restrict__ segkey,
                             unsigned* __restrict__ valkey,
                             unsigned* __restrict__ hist1, int N, int M)
{
  int i = blockIdx.x * blockDim.x + threadIdx.x;
  if (i >= N) return;
  unsigned kk = f2key(pred[i]);
  unsigned vk = (kk == segkey[vox[i]]) ? 0xFFFFFFFFu : kk;
  valkey[i] = vk;
  int row = i / M;
  atomicAdd(&hist1[row * 65536 + (vk >> 16)], 1u);
}

__global__ void k_hist2(const unsigned* __restrict__ valkey,
                        unsigned* __restrict__ hist2,
                        const unsigned* __restrict__ sel, int N, int M)
{
  int i = blockIdx.x * blockDim.x + threadIdx.x;
  if (i >= N) return;
  unsigned vk = valkey[i];
  int row = i / M;
  if ((vk >> 16) == sel[row * 4 + 0])
    atomicAdd(&hist2[row * 65536 + (vk & 0xFFFFu)], 1u);
}

// ---------------------------------------------------------------------------
// radix-select scan (unchanged logic; vectorized partial sums)
// ---------------------------------------------------------------------------
__global__ void k_scan(const unsigned* __restrict__ hist,
                       unsigned* __restrict__ sel,
                       const int* __restrict__ tnum, int M, int pass)
{
  const int row = blockIdx.x;
  const int t = threadIdx.x;  // 256 threads
  const unsigned* h = hist + (size_t)row * 65536;
  __shared__ unsigned part[256];
  const uint4* hv = (const uint4*)(h + t * 256);
  unsigned s = 0;
  for (int i = 0; i < 64; ++i) { uint4 v = hv[i]; s += v.x + v.y + v.z + v.w; }
  part[t] = s;
  __syncthreads();
  if (t == 0) {
    const unsigned k = (unsigned)(M - tnum[0]);
    unsigned cum = (pass == 0) ? 0u : sel[row * 4 + 1];
    int seg = 255;
    for (int i = 0; i < 256; ++i) {
      if (cum + part[i] >= k) { seg = i; break; }
      cum += part[i];
    }
    unsigned bin = 0;
    for (int i = 0; i < 256; ++i) {
      unsigned c = h[seg * 256 + i];
      if (cum + c >= k) { bin = (unsigned)(seg * 256 + i); break; }
      cum += c;
    }
    if (pass == 0) { sel[row * 4 + 0] = bin; sel[row * 4 + 1] = cum; }
    else           { sel[row * 4 + 2] = (sel[row * 4 + 0] << 16) | bin; }
  }
}

__global__ void k_scatter(const int* __restrict__ tidx, float* __restrict__ kt, int n)
{
  int i = blockIdx.x * blockDim.x + threadIdx.x;
  if (i < n) kt[tidx[i]] = 1.0f;
}

// zero rows that are not kept.  keep = (valkey > thr) | is_target
__global__ __launch_bounds__(256) void k_final(const unsigned* __restrict__ valkey,
    const float* __restrict__ kt, const unsigned* __restrict__ sel,
    float* __restrict__ out, int N, int M)
{
  const int wid = threadIdx.x >> 6;
  const int lane = threadIdx.x & 63;
  const int nw = gridDim.x * 4;
  for (int r = blockIdx.x * 4 + wid; r < N; r += nw) {
    unsigned vk = valkey[r];
    float kv = kt[r];
    unsigned thr = sel[(r / M) * 4 + 2];
    bool keep = (vk > thr) || (kv != 0.0f);
    if (!keep)
      *(float2*)&out[(size_t)r * C + lane * 2] = make_float2(0.f, 0.f);
  }
}

// ---------------------------------------------------------------------------
extern "C" void kernel_launch(void* const* d_in, const int* in_sizes, int n_in,
                              void* d_out, int out_size, void* d_ws, size_t ws_size,
                              hipStream_t stream)
{
  const float* fea = (const float*)d_in[0];
  const float* W1  = (const float*)d_in[1];
  const float* b1  = (const float*)d_in[2];
  const float* W2  = (const float*)d_in[3];
  const float* b2  = (const float*)d_in[4];
  const int* vox   = (const int*)d_in[5];
  const int* tidx  = (const int*)d_in[6];
  const int* tnum  = (const int*)d_in[7];

  const int N = in_sizes[5];      // 800000
  const int M = N / BATCH;        // 100000
  const int nT = in_sizes[6];     // 400000

  float* out  = (float*)d_out;
  float* pred = out + (size_t)N * C;
  float* kt   = pred + N;

  char* w = (char*)d_ws;
  unsigned* segkey = (unsigned*)w;                                   // 512KB
  unsigned* hist1  = (unsigned*)(w + (512u << 10));                  // 2MB
  unsigned* hist2  = (unsigned*)(w + (512u << 10) + (2u << 20));     // 2MB
  unsigned* sel    = (unsigned*)(w + (512u << 10) + (4u << 20));     // 4KB
  unsigned* valkey = (unsigned*)(w + (512u << 10) + (4u << 20) + 4096u);

  const size_t zbytes = (512u << 10) + (4u << 20) + 4096u;
  hipMemsetAsync(d_ws, 0, zbytes, stream);
  hipMemsetAsync(kt, 0, (size_t)N * sizeof(float), stream);

  k_scatter<<<(nT + 255) / 256, 256, 0, stream>>>(tidx, kt, nT);
  k_gemm<<<GEMM_BLOCKS, TPB, 0, stream>>>(fea, W1, b1, W2, b2, vox,
                                          out, pred, segkey, N);
  k_mask_hist1<<<(N + 255) / 256, 256, 0, stream>>>(pred, vox, segkey,
                                                    valkey, hist1, N, M);
  k_scan<<<BATCH, 256, 0, stream>>>(hist1, sel, tnum, M, 0);
  k_hist2<<<(N + 255) / 256, 256, 0, stream>>>(valkey, hist2, sel, N, M);
  k_scan<<<BATCH, 256, 0, stream>>>(hist2, sel, tnum, M, 1);
  k_final<<<2048, 256, 0, stream>>>(valkey, kt, sel, out, N, M);
}